// Round 2
// baseline (22728.044 us; speedup 1.0000x reference)
//
#include <hip/hip_runtime.h>

#define TT 512
#define BSZ 64
#define DD 512
#define HH 512

struct Params {
    const float* X;
    const float* Wx[4];   // W_xi, W_xf, W_xo, W_xc   [D][H] row-major
    const float* Wh[4];   // W_hi, W_hf, W_ho, W_hc   [H][H] row-major
    const float* bias[4]; // b_i, b_f, b_o, b_c       [H]
    float* Y;             // [B][T][H]
    float* hbuf;          // ws: 2 * B * H floats (double buffer)
    unsigned int* ctr;    // ws: 8 groups * 64 uints (one counter per group, cacheline-padded)
};

__device__ __forceinline__ float fast_sigmoid(float x) {
    return 1.0f / (1.0f + __expf(-x));
}

__device__ __forceinline__ float fast_tanh(float x) {
    float ax = fabsf(x);
    float e  = __expf(-2.0f * ax);
    float r  = (1.0f - e) / (1.0f + e);
    return copysignf(r, x);
}

__global__ void init_ws(float* hbuf, unsigned int* ctr) {
    int i = blockIdx.x * blockDim.x + threadIdx.x;
    int stride = gridDim.x * blockDim.x;
    for (int k = i; k < 2 * BSZ * HH; k += stride) hbuf[k] = 0.0f;
    if (i < 8 * 64) ctr[i] = 0u;
}

// Persistent LSTM kernel. PLAIN launch (cooperative launch failed silently in R1).
// Grid: 256 blocks x 256 threads. Capacity: <=512 VGPR/wave -> 1 block/CU by VGPR,
// 40KB LDS -> 4/CU by LDS => all 256 blocks co-resident; only 32-block group
// barriers are used (batch groups are fully independent).
//
// 8 groups of 32 blocks. Group g owns batches [8g, 8g+8).
// Block k in group owns hidden units [16k, 16k+16) -> 64 gate columns.
// Thread (c = tid&63, q = tid>>6): gate = c>>4, jj = c&15, K-quarter q.
// Holds W_x[:,col] and W_h[:,col] K-slices (128 floats each) in VGPRs
// (full unroll below is REQUIRED: runtime indexing would spill to scratch).
__global__ __launch_bounds__(256, 1) void lstm_persist(Params p) {
    __shared__ float hs[8 * 512];          // h_prev for 8 batches
    __shared__ float xs[8 * 512];          // x_t for 8 batches
    __shared__ float part[8 * 4 * 64];     // partial gate sums [bb][q][c]

    const int bid  = blockIdx.x;
    const int g    = bid >> 5;
    const int k    = bid & 31;
    const int tid  = threadIdx.x;
    const int c    = tid & 63;
    const int q    = tid >> 6;
    const int gate = c >> 4;
    const int jj   = c & 15;
    const int j    = k * 16 + jj;          // this thread's gate column (within H)
    const int b0   = g * 8;
    const int base = q * 128;              // K-slice start

    const float* WxG = p.Wx[gate];
    const float* WhG = p.Wh[gate];

    // Register-resident weight slices (256 VGPRs; launch_bounds(256,1) allows 512)
    float wx[128], wh[128];
#pragma unroll
    for (int i = 0; i < 128; ++i) {
        wx[i] = WxG[(base + i) * HH + j];
        wh[i] = WhG[(base + i) * HH + j];
    }

    // Cell-update thread state (threads 0..127): (batch bbu, unit jju)
    const int bbu = tid >> 4;
    const int jju = tid & 15;
    const int ju  = k * 16 + jju;
    float cst = 0.0f;
    float bI = 0.f, bF = 0.f, bO = 0.f, bC = 0.f;
    if (tid < 128) {
        bI = p.bias[0][ju];
        bF = p.bias[1][ju];
        bO = p.bias[2][ju];
        bC = p.bias[3][ju];
    }

    unsigned int* ctrp = p.ctr + g * 64;

    for (int t = 0; t < TT; ++t) {
        // ---- stage h_{t-1} and x_t into LDS (coalesced float4) ----
        const float4* hsrc = (const float4*)(p.hbuf + (size_t)(t & 1) * BSZ * HH);
        const float4* xsrc = (const float4*)p.X;
#pragma unroll
        for (int u = 0; u < 4; ++u) {
            int idx = tid + u * 256;            // 0..1023
            int b   = idx >> 7;                 // 0..7
            int dd  = idx & 127;                // float4 index within row
            ((float4*)hs)[b * 128 + dd] = hsrc[(b0 + b) * 128 + dd];
            ((float4*)xs)[b * 128 + dd] = xsrc[((b0 + b) * TT + t) * 128 + dd];
        }
        __syncthreads();

        // ---- partial dot products: acc[bb] = sum_{d in K-slice} h*wh + x*wx ----
        float acc[8];
#pragma unroll
        for (int bb = 0; bb < 8; ++bb) acc[bb] = 0.0f;

#pragma unroll
        for (int i = 0; i < 128; i += 4) {
#pragma unroll
            for (int bb = 0; bb < 8; ++bb) {
                float4 hv = *(const float4*)&hs[bb * 512 + base + i];  // lane-uniform: LDS broadcast
                float4 xv = *(const float4*)&xs[bb * 512 + base + i];
                float a = acc[bb];
                a = fmaf(hv.x, wh[i + 0], a);
                a = fmaf(hv.y, wh[i + 1], a);
                a = fmaf(hv.z, wh[i + 2], a);
                a = fmaf(hv.w, wh[i + 3], a);
                a = fmaf(xv.x, wx[i + 0], a);
                a = fmaf(xv.y, wx[i + 1], a);
                a = fmaf(xv.z, wx[i + 2], a);
                a = fmaf(xv.w, wx[i + 3], a);
                acc[bb] = a;
            }
        }

        // ---- reduce the 4 K-quarters via LDS ----
#pragma unroll
        for (int bb = 0; bb < 8; ++bb)
            part[(bb * 4 + q) * 64 + c] = acc[bb];
        __syncthreads();

        if (tid < 128) {
            float v0 = bI, v1 = bF, v2 = bO, v3 = bC;
#pragma unroll
            for (int qq = 0; qq < 4; ++qq) {
                const float* pr = &part[(bbu * 4 + qq) * 64];
                v0 += pr[0 * 16 + jju];
                v1 += pr[1 * 16 + jju];
                v2 += pr[2 * 16 + jju];
                v3 += pr[3 * 16 + jju];
            }
            float I  = fast_sigmoid(v0);
            float F  = fast_sigmoid(v1);
            float O  = fast_sigmoid(v2);
            float Cd = fast_tanh(v3);
            cst = fmaf(F, cst, I * Cd);
            float h = O * fast_tanh(cst);
            p.hbuf[(size_t)((t + 1) & 1) * BSZ * HH + (b0 + bbu) * HH + ju] = h;
            p.Y[((size_t)(b0 + bbu) * TT + t) * HH + ju] = h;
        }
        // Drain h-stores (syncthreads waits vmcnt) and finish part reads before signaling.
        __syncthreads();

        // ---- group barrier (32 blocks), monotonic counter ----
        // tid 0 publishes with agent-scope release (orders the block's h-stores,
        // which were drained to L2 by the barrier above). EVERY thread spins with
        // an agent-scope acquire load so each thread's subsequent hbuf reads are
        // ordered and its CU's caches are invalidated.
        if (tid == 0) {
            __hip_atomic_fetch_add(ctrp, 1u, __ATOMIC_RELEASE, __HIP_MEMORY_SCOPE_AGENT);
        }
        const unsigned int need = 32u * (unsigned int)(t + 1);
        while (__hip_atomic_load(ctrp, __ATOMIC_ACQUIRE, __HIP_MEMORY_SCOPE_AGENT) < need) {
            __builtin_amdgcn_s_sleep(2);
        }
        // No extra __syncthreads needed: each thread independently passed the
        // acquire point; LDS hs/xs rewrites at t+1 are fenced by the post-stage
        // __syncthreads, and all compute-phase hs/xs reads finished before the
        // pre-signal __syncthreads.
    }
}

extern "C" void kernel_launch(void* const* d_in, const int* in_sizes, int n_in,
                              void* d_out, int out_size, void* d_ws, size_t ws_size,
                              hipStream_t stream) {
    Params p;
    p.X       = (const float*)d_in[0];
    p.Wx[0]   = (const float*)d_in[1];
    p.Wh[0]   = (const float*)d_in[2];
    p.bias[0] = (const float*)d_in[3];
    p.Wx[1]   = (const float*)d_in[4];
    p.Wh[1]   = (const float*)d_in[5];
    p.bias[1] = (const float*)d_in[6];
    p.Wx[2]   = (const float*)d_in[7];
    p.Wh[2]   = (const float*)d_in[8];
    p.bias[2] = (const float*)d_in[9];
    p.Wx[3]   = (const float*)d_in[10];
    p.Wh[3]   = (const float*)d_in[11];
    p.bias[3] = (const float*)d_in[12];
    p.Y       = (float*)d_out;
    p.hbuf    = (float*)d_ws;
    p.ctr     = (unsigned int*)((char*)d_ws + (size_t)2 * BSZ * HH * sizeof(float));

    // ws is poisoned 0xAA before every timed launch: zero h0 double-buffer + barrier counters
    init_ws<<<64, 256, 0, stream>>>(p.hbuf, p.ctr);

    lstm_persist<<<dim3(256), dim3(256), 0, stream>>>(p);
}